// Round 6
// baseline (129.865 us; speedup 1.0000x reference)
//
#include <hip/hip_runtime.h>
#include <stdint.h>

typedef __attribute__((ext_vector_type(8))) short bf16x8;
typedef __attribute__((ext_vector_type(4))) short bf16x4;
typedef __attribute__((ext_vector_type(4))) float f32x4;
typedef unsigned short u16t;

#define DEVINL static __device__ __forceinline__

DEVINL u16t f2bf(float f) {
  union { float f; unsigned u; } v; v.f = f;
  return (u16t)((v.u + 0x7FFFu + ((v.u >> 16) & 1u)) >> 16);  // RNE, inputs finite
}
DEVINL float bf2f(u16t u) {
  union { unsigned u; float f; } v; v.u = ((unsigned)u) << 16; return v.f;
}

DEVINL float exp2_fast(float x) {
  float r; asm("v_exp_f32 %0, %1" : "=v"(r) : "v"(x)); return r;
}
DEVINL unsigned cvt_pk_bf16(float a, float b) {  // lo16=bf16(a), hi16=bf16(b)
  unsigned r; asm("v_cvt_pk_bf16_f32 %0, %1, %2" : "=v"(r) : "v"(a), "v"(b)); return r;
}
DEVINL float max3f(float a, float b, float c) {
  float r; asm("v_max3_f32 %0, %1, %2, %3" : "=v"(r) : "v"(a), "v"(b), "v"(c)); return r;
}

DEVINL void gload16(const void* g, void* l) {
  __builtin_amdgcn_global_load_lds((const __attribute__((address_space(1))) void*)g,
                                   (__attribute__((address_space(3))) void*)l, 16, 0, 0);
}

// ---------------- fp32 -> bf16 convert (all 5 tensors, one launch) ----------------
__global__ __launch_bounds__(256)
void cvt5_kernel(const float* __restrict__ x, const float* __restrict__ wq,
                 const float* __restrict__ wk, const float* __restrict__ wv,
                 const float* __restrict__ wo, u16t* __restrict__ x_bf,
                 u16t* __restrict__ wqkv, u16t* __restrict__ wo_bf) {
  const int bid = blockIdx.x;
  const float* src; u16t* dst; int off;
  if (bid < 2048) { src = x; dst = x_bf; off = bid * 2048; }
  else {
    const int j = bid - 2048, sel = j >> 9;
    off = (j & 511) * 2048;
    if (sel == 0)      { src = wq; dst = wqkv; }
    else if (sel == 1) { src = wk; dst = wqkv + 1048576; }
    else if (sel == 2) { src = wv; dst = wqkv + 2097152; }
    else               { src = wo; dst = wo_bf; }
  }
  const int i = off + threadIdx.x * 8;
  float4 a = *(const float4*)(src + i);
  float4 b = *(const float4*)(src + i + 4);
  union { bf16x8 v; u16t u[8]; } o;
  o.u[0] = f2bf(a.x); o.u[1] = f2bf(a.y); o.u[2] = f2bf(a.z); o.u[3] = f2bf(a.w);
  o.u[4] = f2bf(b.x); o.u[5] = f2bf(b.y); o.u[6] = f2bf(b.z); o.u[7] = f2bf(b.w);
  *(bf16x8*)(dst + i) = o.v;
}

// ---------------- bf16 GEMM: C[M,N] = A[M,K] * Bw[N,K]^T + bias ----------------
// M=4096, K=1024. MODE 0: N=3072 (Wq|Wk|Wv): Q scaled by 0.125*log2(e), V written
// transposed as Vt[b][h][d][s]. MODE 1: N=1024 (Wo), fp32 out.
template <int MODE>
__global__ __launch_bounds__(256, 2)
void gemm_kernel(const u16t* __restrict__ A, const u16t* __restrict__ Bw,
                 const float* __restrict__ bias0, const float* __restrict__ bias1,
                 const float* __restrict__ bias2, void* __restrict__ outp) {
  __shared__ __attribute__((aligned(16))) u16t As[128 * 64];
  __shared__ __attribute__((aligned(16))) u16t Bs[128 * 64];
  const int tid = threadIdx.x;
  const int w = tid >> 6, l = tid & 63;
  const int wm = w >> 1, wn = w & 1;
  const int bm = blockIdx.x, bn = blockIdx.y;
  const int g = l >> 4, r16 = l & 15;
  const int srow = l >> 3, sslot = l & 7;

  f32x4 acc[4][4];
#pragma unroll
  for (int m = 0; m < 4; ++m)
#pragma unroll
    for (int n = 0; n < 4; ++n) acc[m][n] = f32x4{0.f, 0.f, 0.f, 0.f};

  const size_t arow0 = (size_t)bm * 128;
  const size_t brow0 = (size_t)bn * 128;

  for (int kt = 0; kt < 16; ++kt) {
    __syncthreads();
#pragma unroll
    for (int i = 0; i < 4; ++i) {
      const int row = (i * 4 + w) * 8 + srow;
      const int colA = kt * 64 + ((sslot ^ (row & 7)) * 8);
      gload16(A + (arow0 + row) * 1024 + colA, (char*)As + (i * 4 + w) * 1024);
      gload16(Bw + (brow0 + row) * 1024 + colA, (char*)Bs + (i * 4 + w) * 1024);
    }
    asm volatile("s_waitcnt vmcnt(0)" ::: "memory");
    __syncthreads();
#pragma unroll
    for (int kk = 0; kk < 2; ++kk) {
      bf16x8 af[4], bfr[4];
#pragma unroll
      for (int m = 0; m < 4; ++m) {
        const int rr = wm * 64 + m * 16 + r16;
        af[m] = *(const bf16x8*)((const char*)As + rr * 128 + (((kk * 4 + g) ^ (rr & 7)) * 16));
      }
#pragma unroll
      for (int n = 0; n < 4; ++n) {
        const int rr = wn * 64 + n * 16 + r16;
        bfr[n] = *(const bf16x8*)((const char*)Bs + rr * 128 + (((kk * 4 + g) ^ (rr & 7)) * 16));
      }
#pragma unroll
      for (int m = 0; m < 4; ++m)
#pragma unroll
        for (int n = 0; n < 4; ++n)
          acc[m][n] = __builtin_amdgcn_mfma_f32_16x16x32_bf16(af[m], bfr[n], acc[m][n], 0, 0, 0);
    }
  }

  if (MODE == 0) {
    const int mat = bn >> 3;  // 0=Q,1=K,2=V
    if (mat == 2) {
      u16t* vt = (u16t*)outp + 8388608u;
#pragma unroll
      for (int n = 0; n < 4; ++n) {
        const int col = ((bn & 7) * 128) + wn * 64 + n * 16 + r16;  // h*64+d
        const int hh = col >> 6, dd = col & 63;
        const float bv = bias2[col];
#pragma unroll
        for (int m = 0; m < 4; ++m) {
          const int row0 = bm * 128 + wm * 64 + m * 16 + g * 4;
          const int b_ = row0 >> 11, s_ = row0 & 2047;
          union { bf16x4 v; u16t u[4]; } o4;
#pragma unroll
          for (int i = 0; i < 4; ++i) o4.u[i] = f2bf(acc[m][n][i] + bv);
          *(bf16x4*)(vt + ((size_t)(b_ * 16 + hh) * 64 + dd) * 2048 + s_) = o4.v;
        }
      }
    } else {
      const float* bias = (mat == 0) ? bias0 : bias1;
      // Q: fold 1/sqrt(64) * log2(e) so attention works in exp2 domain
      const float scale = (mat == 0) ? 0.18033688f : 1.0f;
      u16t* o = (u16t*)outp + (size_t)mat * 4194304u;
#pragma unroll
      for (int n = 0; n < 4; ++n) {
        const int col = ((bn & 7) * 128) + wn * 64 + n * 16 + r16;
        const float bv = bias[col];
#pragma unroll
        for (int m = 0; m < 4; ++m) {
          const int row = bm * 128 + wm * 64 + m * 16 + g * 4;
#pragma unroll
          for (int i = 0; i < 4; ++i)
            o[(size_t)(row + i) * 1024 + col] = f2bf((acc[m][n][i] + bv) * scale);
        }
      }
    }
  } else {
    float* o = (float*)outp;
#pragma unroll
    for (int n = 0; n < 4; ++n) {
      const int col = bn * 128 + wn * 64 + n * 16 + r16;
      const float bv = bias0[col];
#pragma unroll
      for (int m = 0; m < 4; ++m) {
        const int row = bm * 128 + wm * 64 + m * 16 + g * 4;
#pragma unroll
        for (int i = 0; i < 4; ++i)
          o[(size_t)(row + i) * 1024 + col] = acc[m][n][i] + bv;
      }
    }
  }
}

// ---------------- flash attention with ALiBi, KV-split=2 ----------------
// exp2 domain, reverse tile order within split, bias folded into MFMA C-init.
// grid (32 qt, 32 bh, 2 split); split s covers key tiles [32s,32s+32), 32 iters.
// Writes UNNORMALIZED partial O (bf16) + per-row (m,l) fp32; combine_kernel merges.
// LDS: K ring3 (3x4KB, [32 keys][64 d] rows=128B) + V ring2 (2x4KB, paired-row
// lines: line=d>>1, slot=((d&1)<<2|g)^(line&3)) = 20480 B -> 8 blocks/CU (100% cap).
// Counted vmcnt(1)/iter: issue V(t+1) then K(t+2) after the barrier.
__global__ __launch_bounds__(256, 2)
void attn_kernel(const u16t* __restrict__ Qb, const u16t* __restrict__ Kb,
                 const u16t* __restrict__ Vtb, const float* __restrict__ slopes,
                 u16t* __restrict__ O0, u16t* __restrict__ O1,
                 float2* __restrict__ ML) {
  __shared__ __attribute__((aligned(16))) u16t Kl[3][2048];  // 3 x [32 keys][64 d]
  __shared__ __attribute__((aligned(16))) u16t Vl[2][2048];  // 2 x 32 lines x 128B
  const int tid = threadIdx.x;
  const int w = tid >> 6, l = tid & 63;
  const int g = l >> 4, r = l & 15;
  const int qt = blockIdx.x, bh = blockIdx.y, sp = blockIdx.z;
  const int b = bh >> 4, h = bh & 15;
  const float slope2 = slopes[h] * 1.44269504f;
  const int qpos = qt * 64 + w * 16 + r;
  const size_t base = (size_t)b * 2097152 + (size_t)h * 64;

  const u16t* qrow = Qb + base + (size_t)qpos * 1024;
  const bf16x8 qf0 = *(const bf16x8*)(qrow + g * 8);
  const bf16x8 qf1 = *(const bf16x8*)(qrow + 32 + g * 8);
  asm volatile("s_waitcnt vmcnt(0)" ::: "memory");  // Q in regs; vmcnt clean

  // K A-frag offsets: row perm sigma(r)=8*(r>>2)+(r&3), tiles toff {0,4};
  // mask (row&3)^((row>>1)&4) — proven 0-conflict (R3 geometry).
  const int sig = 8 * (r >> 2) + (r & 3);
  const int toffs[2] = {0, 4};
  int koff[2][2], voff[4];
#pragma unroll
  for (int t = 0; t < 2; ++t) {
    const int row = toffs[t] + sig;
    const int mk = (row & 3) ^ ((row >> 1) & 4);
#pragma unroll
    for (int hh = 0; hh < 2; ++hh) koff[t][hh] = row * 128 + (((hh * 4 + g) ^ mk) * 16);
  }
  // V read: lane (g,r), db: d=16db+r; line=8db+(r>>1); slot=((r&1)<<2|g)^((r>>1)&3)
#pragma unroll
  for (int db = 0; db < 4; ++db)
    voff[db] = (8 * db + (r >> 1)) * 128 + ((((((r & 1) << 2) | g)) ^ ((r >> 1) & 3)) * 16);

  // staging source geometry (LDS dest linear, source pre-swizzled)
  const int kline_s = w * 8 + (l >> 3);             // 0..31
  const int ku_s = ((l & 7) ^ ((kline_s & 3) ^ ((kline_s >> 1) & 4))) * 8;
  const int vu_s = (l & 7) ^ (kline_s & 3);         // V: u = slot ^ (line&3)
  const int vd_s = 2 * kline_s + (vu_s >> 2);       // global d row
  const int vcol_s = (vu_s & 3) * 8;                // key sub-offset

  // ALiBi C-init: cv[t][i] = slope2 * local_j for st[t][i] <-> key toff[t]+8g+i
  f32x4 cv[2];
#pragma unroll
  for (int t = 0; t < 2; ++t)
#pragma unroll
    for (int i = 0; i < 4; ++i) cv[t][i] = slope2 * (float)(toffs[t] + 8 * g + i);

  const float d32 = slope2 * 32.f;
  float mj = -3.0e38f;
  f32x4 oc[4], sacc;
#pragma unroll
  for (int d = 0; d < 4; ++d) oc[d] = f32x4{0.f, 0.f, 0.f, 0.f};
  sacc = f32x4{0.f, 0.f, 0.f, 0.f};
  union { bf16x8 v; u16t u[8]; } ones;
#pragma unroll
  for (int i = 0; i < 8; ++i) ones.u[i] = 0x3F80;  // 1.0 bf16

  const u16t* Krow = Kb + base;
  const u16t* Vrow = Vtb + (size_t)(b * 16 + h) * 131072;  // [64][2048]
  const int kt0 = sp * 32 + 31;

#define STAGE_K(kt_, b_)                                                          \
  gload16(Krow + (size_t)((kt_) * 32 + kline_s) * 1024 + ku_s,                    \
          (char*)Kl + (b_) * 4096 + w * 1024);
#define STAGE_V(kt_, b_)                                                          \
  gload16(Vrow + (size_t)vd_s * 2048 + (kt_) * 32 + vcol_s,                       \
          (char*)Vl + (b_) * 4096 + w * 1024);

  // prologue: K(t0)->k0, V(t0)->v0, K(t0-1)->k1   [oldest..newest]
  STAGE_K(kt0, 0)
  STAGE_V(kt0, 0)
  STAGE_K(kt0 - 1, 1)

  for (int it = 0; it < 32; ++it) {
    const int kt = kt0 - it;
    const int kbuf = it % 3, vbuf = it & 1;
    // own-tile K,V are the 2 oldest; next K may stay in flight
    if (it == 31) { asm volatile("s_waitcnt vmcnt(0)" ::: "memory"); }
    else          { asm volatile("s_waitcnt vmcnt(1)" ::: "memory"); }
    __builtin_amdgcn_s_barrier();   // all waves: tile staged, prev compute done
    asm volatile("" ::: "memory");  // fence IR motion across the barrier
    if (it + 1 < 32) STAGE_V(kt - 1, vbuf ^ 1)   // V first (keeps wait at vmcnt(1))
    if (it + 2 < 32) STAGE_K(kt - 2, (it + 2) % 3)
    if (it) mj += d32;              // local-bias coordinate shift

    const char* KB = (const char*)Kl + kbuf * 4096;
    const char* VB = (const char*)Vl + vbuf * 4096;

    f32x4 st[2];
#pragma unroll
    for (int t = 0; t < 2; ++t) {
      st[t] = __builtin_amdgcn_mfma_f32_16x16x32_bf16(
          *(const bf16x8*)(KB + koff[t][0]), qf0, cv[t], 0, 0, 0);
      st[t] = __builtin_amdgcn_mfma_f32_16x16x32_bf16(
          *(const bf16x8*)(KB + koff[t][1]), qf1, st[t], 0, 0, 0);
    }

    const float m1 = max3f(st[0][0], st[0][1], st[0][2]);
    const float m2 = max3f(st[0][3], st[1][0], st[1][1]);
    const float m3 = max3f(st[1][2], st[1][3], m1);
    const float tm = fmaxf(m2, m3);
    if (__any(tm > mj)) {  // rare: reverse order => max found in first tiles
      float tr = fmaxf(tm, __shfl_xor(tm, 16));
      tr = fmaxf(tr, __shfl_xor(tr, 32));
      const float mn = fmaxf(mj, tr);
      const float corr = exp2_fast(mj - mn);
#pragma unroll
      for (int d = 0; d < 4; ++d) {
        oc[d][0] *= corr; oc[d][1] *= corr; oc[d][2] *= corr; oc[d][3] *= corr;
      }
      sacc[0] *= corr; sacc[1] *= corr; sacc[2] *= corr; sacc[3] *= corr;
      mj = mn;
    }

    float pe[8];
#pragma unroll
    for (int t = 0; t < 2; ++t)
#pragma unroll
      for (int i = 0; i < 4; ++i) pe[t * 4 + i] = exp2_fast(st[t][i] - mj);
    union { bf16x8 v; unsigned q[4]; } pb;
#pragma unroll
    for (int j = 0; j < 4; ++j) pb.q[j] = cvt_pk_bf16(pe[j * 2], pe[j * 2 + 1]);

#pragma unroll
    for (int db = 0; db < 4; ++db)
      oc[db] = __builtin_amdgcn_mfma_f32_16x16x32_bf16(
          *(const bf16x8*)(VB + voff[db]), pb.v, oc[db], 0, 0, 0);
    sacc = __builtin_amdgcn_mfma_f32_16x16x32_bf16(ones.v, pb.v, sacc, 0, 0, 0);
  }
#undef STAGE_K
#undef STAGE_V

  // write unnormalized partial O + (m_global, l)
  u16t* op = (sp ? O1 : O0) + base + (size_t)qpos * 1024;
#pragma unroll
  for (int d = 0; d < 4; ++d) {
    union { bf16x4 v; u16t u[4]; } o4;
#pragma unroll
    for (int i = 0; i < 4; ++i) o4.u[i] = f2bf(oc[d][i]);
    *(bf16x4*)(op + d * 16 + g * 4) = o4.v;
  }
  if (l < 16) {  // g==0 lanes hold per-row m (mj) and l (sacc[0])
    const float m_global = mj + (sp ? slope2 * 1024.f : 0.f);
    ML[((size_t)(sp * 2 + b) * 16 + h) * 2048 + qpos] = float2{m_global, sacc[0]};
  }
}

// ---------------- combine two KV-split partials -> normalized ctx ----------------
__global__ __launch_bounds__(256)
void combine_kernel(u16t* __restrict__ O0 /* in-out: becomes ctx */,
                    const u16t* __restrict__ O1, const float2* __restrict__ ML) {
  const int idx = blockIdx.x * 256 + threadIdx.x;  // 524288 threads x 8 elems
  const int colg = idx & 127, tok = idx >> 7;
  const int b = tok >> 11, s = tok & 2047, h = colg >> 3;
  const float2 ml0 = ML[((size_t)(0 + b) * 16 + h) * 2048 + s];
  const float2 ml1 = ML[((size_t)(2 + b) * 16 + h) * 2048 + s];
  const float M = fmaxf(ml0.x, ml1.x);
  const float e0 = exp2_fast(ml0.x - M), e1 = exp2_fast(ml1.x - M);
  const float invL = 1.f / (ml0.y * e0 + ml1.y * e1);
  const float w0 = e0 * invL, w1 = e1 * invL;
  union { bf16x8 v; u16t u[8]; } a, c, o;
  a.v = *(const bf16x8*)(O0 + (size_t)idx * 8);
  c.v = *(const bf16x8*)(O1 + (size_t)idx * 8);
#pragma unroll
  for (int i = 0; i < 8; ++i) o.u[i] = f2bf(bf2f(a.u[i]) * w0 + bf2f(c.u[i]) * w1);
  *(bf16x8*)(O0 + (size_t)idx * 8) = o.v;
}

extern "C" void kernel_launch(void* const* d_in, const int* in_sizes, int n_in,
                              void* d_out, int out_size, void* d_ws, size_t ws_size,
                              hipStream_t stream) {
  const float* x = (const float*)d_in[0];
  const float* Wq = (const float*)d_in[1];
  const float* bq = (const float*)d_in[2];
  const float* Wk = (const float*)d_in[3];
  const float* bk = (const float*)d_in[4];
  const float* Wv = (const float*)d_in[5];
  const float* bv = (const float*)d_in[6];
  const float* Wo = (const float*)d_in[7];
  const float* bo = (const float*)d_in[8];
  const float* slopes = (const float*)d_in[9];
  if (ws_size < (size_t)(48u << 20)) return;
  char* ws = (char*)d_ws;
  u16t* x_bf = (u16t*)(ws);                  //  8 MB: x bf16 (dead after gemm0)
  u16t* wqkv = (u16t*)(ws + (8u << 20));     //  6 MB: Wq|Wk|Wv (dead after gemm0)
  u16t* wo_bf = (u16t*)(ws + (14u << 20));   //  2 MB: Wo bf16
  u16t* q_bf = (u16t*)(ws + (16u << 20));    // 24 MB: Q | K | Vt bf16
  u16t* ctx_bf = (u16t*)(ws + (40u << 20));  //  8 MB: ctx / split-0 partial
  u16t* part1 = (u16t*)(ws);                 //  8 MB: split-1 partial (reuses x_bf)
  float2* ml = (float2*)(ws + (8u << 20));   //  1 MB: (m,l) per split/row (reuses wqkv)

  cvt5_kernel<<<4096, 256, 0, stream>>>(x, Wq, Wk, Wv, Wo, x_bf, wqkv, wo_bf);
  gemm_kernel<0><<<dim3(32, 24), 256, 0, stream>>>(x_bf, wqkv, bq, bk, bv, (void*)q_bf);
  attn_kernel<<<dim3(32, 32, 2), 256, 0, stream>>>(q_bf, q_bf + 4194304, q_bf + 8388608,
                                                   slopes, ctx_bf, part1, ml);
  combine_kernel<<<2048, 256, 0, stream>>>(ctx_bf, part1, ml);
  gemm_kernel<1><<<dim3(32, 8), 256, 0, stream>>>(ctx_bf, wo_bf, bo, bo, bo, d_out);
}

// Round 7
// 116.043 us; speedup vs baseline: 1.1191x; 1.1191x over previous
//
#include <hip/hip_runtime.h>
#include <stdint.h>

typedef __attribute__((ext_vector_type(8))) short bf16x8;
typedef __attribute__((ext_vector_type(4))) short bf16x4;
typedef __attribute__((ext_vector_type(4))) float f32x4;
typedef unsigned short u16t;

#define DEVINL static __device__ __forceinline__

DEVINL u16t f2bf(float f) {
  union { float f; unsigned u; } v; v.f = f;
  return (u16t)((v.u + 0x7FFFu + ((v.u >> 16) & 1u)) >> 16);  // RNE, inputs finite
}
DEVINL float bf2f(u16t u) {
  union { unsigned u; float f; } v; v.u = ((unsigned)u) << 16; return v.f;
}

DEVINL float exp2_fast(float x) {
  float r; asm("v_exp_f32 %0, %1" : "=v"(r) : "v"(x)); return r;
}
DEVINL unsigned cvt_pk_bf16(float a, float b) {  // lo16=bf16(a), hi16=bf16(b)
  unsigned r; asm("v_cvt_pk_bf16_f32 %0, %1, %2" : "=v"(r) : "v"(a), "v"(b)); return r;
}
DEVINL float max3f(float a, float b, float c) {
  float r; asm("v_max3_f32 %0, %1, %2, %3" : "=v"(r) : "v"(a), "v"(b), "v"(c)); return r;
}

DEVINL void gload16(const void* g, void* l) {
  __builtin_amdgcn_global_load_lds((const __attribute__((address_space(1))) void*)g,
                                   (__attribute__((address_space(3))) void*)l, 16, 0, 0);
}

// ---------------- fp32 -> bf16 convert (all 5 tensors, one launch) ----------------
__global__ __launch_bounds__(256)
void cvt5_kernel(const float* __restrict__ x, const float* __restrict__ wq,
                 const float* __restrict__ wk, const float* __restrict__ wv,
                 const float* __restrict__ wo, u16t* __restrict__ x_bf,
                 u16t* __restrict__ wqkv, u16t* __restrict__ wo_bf) {
  const int bid = blockIdx.x;
  const float* src; u16t* dst; int off;
  if (bid < 2048) { src = x; dst = x_bf; off = bid * 2048; }
  else {
    const int j = bid - 2048, sel = j >> 9;
    off = (j & 511) * 2048;
    if (sel == 0)      { src = wq; dst = wqkv; }
    else if (sel == 1) { src = wk; dst = wqkv + 1048576; }
    else if (sel == 2) { src = wv; dst = wqkv + 2097152; }
    else               { src = wo; dst = wo_bf; }
  }
  const int i = off + threadIdx.x * 8;
  float4 a = *(const float4*)(src + i);
  float4 b = *(const float4*)(src + i + 4);
  union { bf16x8 v; u16t u[8]; } o;
  o.u[0] = f2bf(a.x); o.u[1] = f2bf(a.y); o.u[2] = f2bf(a.z); o.u[3] = f2bf(a.w);
  o.u[4] = f2bf(b.x); o.u[5] = f2bf(b.y); o.u[6] = f2bf(b.z); o.u[7] = f2bf(b.w);
  *(bf16x8*)(dst + i) = o.v;
}

// ---------------- bf16 GEMM: C[M,N] = A[M,K] * Bw[N,K]^T + bias ----------------
// M=4096, K=1024. MODE 0: N=3072 (Wq|Wk|Wv): Q scaled by 0.125*log2(e), V written
// transposed as Vt[b][h][d][s]. MODE 1: N=1024 (Wo), fp32 out.
template <int MODE>
__global__ __launch_bounds__(256, 2)
void gemm_kernel(const u16t* __restrict__ A, const u16t* __restrict__ Bw,
                 const float* __restrict__ bias0, const float* __restrict__ bias1,
                 const float* __restrict__ bias2, void* __restrict__ outp) {
  __shared__ __attribute__((aligned(16))) u16t As[128 * 64];
  __shared__ __attribute__((aligned(16))) u16t Bs[128 * 64];
  const int tid = threadIdx.x;
  const int w = tid >> 6, l = tid & 63;
  const int wm = w >> 1, wn = w & 1;
  const int bm = blockIdx.x, bn = blockIdx.y;
  const int g = l >> 4, r16 = l & 15;
  const int srow = l >> 3, sslot = l & 7;

  f32x4 acc[4][4];
#pragma unroll
  for (int m = 0; m < 4; ++m)
#pragma unroll
    for (int n = 0; n < 4; ++n) acc[m][n] = f32x4{0.f, 0.f, 0.f, 0.f};

  const size_t arow0 = (size_t)bm * 128;
  const size_t brow0 = (size_t)bn * 128;

  for (int kt = 0; kt < 16; ++kt) {
    __syncthreads();
#pragma unroll
    for (int i = 0; i < 4; ++i) {
      const int row = (i * 4 + w) * 8 + srow;
      const int colA = kt * 64 + ((sslot ^ (row & 7)) * 8);
      gload16(A + (arow0 + row) * 1024 + colA, (char*)As + (i * 4 + w) * 1024);
      gload16(Bw + (brow0 + row) * 1024 + colA, (char*)Bs + (i * 4 + w) * 1024);
    }
    asm volatile("s_waitcnt vmcnt(0)" ::: "memory");
    __syncthreads();
#pragma unroll
    for (int kk = 0; kk < 2; ++kk) {
      bf16x8 af[4], bfr[4];
#pragma unroll
      for (int m = 0; m < 4; ++m) {
        const int rr = wm * 64 + m * 16 + r16;
        af[m] = *(const bf16x8*)((const char*)As + rr * 128 + (((kk * 4 + g) ^ (rr & 7)) * 16));
      }
#pragma unroll
      for (int n = 0; n < 4; ++n) {
        const int rr = wn * 64 + n * 16 + r16;
        bfr[n] = *(const bf16x8*)((const char*)Bs + rr * 128 + (((kk * 4 + g) ^ (rr & 7)) * 16));
      }
#pragma unroll
      for (int m = 0; m < 4; ++m)
#pragma unroll
        for (int n = 0; n < 4; ++n)
          acc[m][n] = __builtin_amdgcn_mfma_f32_16x16x32_bf16(af[m], bfr[n], acc[m][n], 0, 0, 0);
    }
  }

  if (MODE == 0) {
    const int mat = bn >> 3;  // 0=Q,1=K,2=V
    if (mat == 2) {
      u16t* vt = (u16t*)outp + 8388608u;
#pragma unroll
      for (int n = 0; n < 4; ++n) {
        const int col = ((bn & 7) * 128) + wn * 64 + n * 16 + r16;  // h*64+d
        const int hh = col >> 6, dd = col & 63;
        const float bv = bias2[col];
#pragma unroll
        for (int m = 0; m < 4; ++m) {
          const int row0 = bm * 128 + wm * 64 + m * 16 + g * 4;
          const int b_ = row0 >> 11, s_ = row0 & 2047;
          union { bf16x4 v; u16t u[4]; } o4;
#pragma unroll
          for (int i = 0; i < 4; ++i) o4.u[i] = f2bf(acc[m][n][i] + bv);
          *(bf16x4*)(vt + ((size_t)(b_ * 16 + hh) * 64 + dd) * 2048 + s_) = o4.v;
        }
      }
    } else {
      const float* bias = (mat == 0) ? bias0 : bias1;
      // Q: fold 1/sqrt(64) * log2(e) so attention works in exp2 domain
      const float scale = (mat == 0) ? 0.18033688f : 1.0f;
      u16t* o = (u16t*)outp + (size_t)mat * 4194304u;
#pragma unroll
      for (int n = 0; n < 4; ++n) {
        const int col = ((bn & 7) * 128) + wn * 64 + n * 16 + r16;
        const float bv = bias[col];
#pragma unroll
        for (int m = 0; m < 4; ++m) {
          const int row = bm * 128 + wm * 64 + m * 16 + g * 4;
#pragma unroll
          for (int i = 0; i < 4; ++i)
            o[(size_t)(row + i) * 1024 + col] = f2bf((acc[m][n][i] + bv) * scale);
        }
      }
    }
  } else {
    float* o = (float*)outp;
#pragma unroll
    for (int n = 0; n < 4; ++n) {
      const int col = bn * 128 + wn * 64 + n * 16 + r16;
      const float bv = bias0[col];
#pragma unroll
      for (int m = 0; m < 4; ++m) {
        const int row = bm * 128 + wm * 64 + m * 16 + g * 4;
#pragma unroll
        for (int i = 0; i < 4; ++i)
          o[(size_t)(row + i) * 1024 + col] = acc[m][n][i] + bv;
      }
    }
  }
}

// ---------------- flash attention with ALiBi, KV-split=2 + windowing ----------------
// Softmax weight ~ exp2(s_j + slope2*j): ramps with key index j, identically for all
// queries. Keys with slope2*(2047-j) > 26 are < ~1e-3 of the output -> skip their
// tiles entirely (window depends only on h; deterministic). Per split, process only
// the last n tiles; n==0 blocks write (m=-inf, l=0) and exit (combine weights
// them to exactly 0). Otherwise identical to R6: exp2 domain, reverse order, bias
// in MFMA C-init, K ring3 + V ring2 LDS (20480 B), counted vmcnt(1), ones-MFMA
// row-sum, unnormalized partial O + (m,l) out.
__global__ __launch_bounds__(256, 2)
void attn_kernel(const u16t* __restrict__ Qb, const u16t* __restrict__ Kb,
                 const u16t* __restrict__ Vtb, const float* __restrict__ slopes,
                 u16t* __restrict__ O0, u16t* __restrict__ O1,
                 float2* __restrict__ ML) {
  __shared__ __attribute__((aligned(16))) u16t Kl[3][2048];  // 3 x [32 keys][64 d]
  __shared__ __attribute__((aligned(16))) u16t Vl[2][2048];  // 2 x 32 lines x 128B
  const int tid = threadIdx.x;
  const int w = tid >> 6, l = tid & 63;
  const int g = l >> 4, r = l & 15;
  const int qt = blockIdx.x, bh = blockIdx.y, sp = blockIdx.z;
  const int b = bh >> 4, h = bh & 15;
  const float slope2 = slopes[h] * 1.44269504f;
  const int qpos = qt * 64 + w * 16 + r;
  const size_t base = (size_t)b * 2097152 + (size_t)h * 64;

  // ---- ALiBi window: only the last W=26/slope2 keys matter ----
  const float Wkeys = 26.0f / slope2;
  const int wt = (int)ceilf(Wkeys * 0.03125f);          // tiles from the end
  const int n = sp ? (wt < 32 ? wt : 32)
                   : (wt - 32 < 0 ? 0 : (wt - 32 < 32 ? wt - 32 : 32));
  if (n == 0) {  // this split contributes nothing measurable
    if (l < 16 && w == 0)
      ML[((size_t)(sp * 2 + b) * 16 + h) * 2048 + qt * 64 + r] = float2{-3.0e38f, 0.f};
    if (l < 16)
      ML[((size_t)(sp * 2 + b) * 16 + h) * 2048 + qpos] = float2{-3.0e38f, 0.f};
    return;
  }

  const u16t* qrow = Qb + base + (size_t)qpos * 1024;
  const bf16x8 qf0 = *(const bf16x8*)(qrow + g * 8);
  const bf16x8 qf1 = *(const bf16x8*)(qrow + 32 + g * 8);
  asm volatile("s_waitcnt vmcnt(0)" ::: "memory");  // Q in regs; vmcnt clean

  // K A-frag offsets: row perm sigma(r)=8*(r>>2)+(r&3), tiles toff {0,4};
  // mask (row&3)^((row>>1)&4) — proven 0-conflict (R3 geometry).
  const int sig = 8 * (r >> 2) + (r & 3);
  const int toffs[2] = {0, 4};
  int koff[2][2], voff[4];
#pragma unroll
  for (int t = 0; t < 2; ++t) {
    const int row = toffs[t] + sig;
    const int mk = (row & 3) ^ ((row >> 1) & 4);
#pragma unroll
    for (int hh = 0; hh < 2; ++hh) koff[t][hh] = row * 128 + (((hh * 4 + g) ^ mk) * 16);
  }
  // V read: lane (g,r), db: d=16db+r; line=8db+(r>>1); slot=((r&1)<<2|g)^((r>>1)&3)
#pragma unroll
  for (int db = 0; db < 4; ++db)
    voff[db] = (8 * db + (r >> 1)) * 128 + ((((((r & 1) << 2) | g)) ^ ((r >> 1) & 3)) * 16);

  // staging source geometry (LDS dest linear, source pre-swizzled)
  const int kline_s = w * 8 + (l >> 3);             // 0..31
  const int ku_s = ((l & 7) ^ ((kline_s & 3) ^ ((kline_s >> 1) & 4))) * 8;
  const int vu_s = (l & 7) ^ (kline_s & 3);         // V: u = slot ^ (line&3)
  const int vd_s = 2 * kline_s + (vu_s >> 2);       // global d row
  const int vcol_s = (vu_s & 3) * 8;                // key sub-offset

  // ALiBi C-init: cv[t][i] = slope2 * local_j for st[t][i] <-> key toff[t]+8g+i
  f32x4 cv[2];
#pragma unroll
  for (int t = 0; t < 2; ++t)
#pragma unroll
    for (int i = 0; i < 4; ++i) cv[t][i] = slope2 * (float)(toffs[t] + 8 * g + i);

  const float d32 = slope2 * 32.f;
  float mj = -3.0e38f;
  f32x4 oc[4], sacc;
#pragma unroll
  for (int d = 0; d < 4; ++d) oc[d] = f32x4{0.f, 0.f, 0.f, 0.f};
  sacc = f32x4{0.f, 0.f, 0.f, 0.f};
  union { bf16x8 v; u16t u[8]; } ones;
#pragma unroll
  for (int i = 0; i < 8; ++i) ones.u[i] = 0x3F80;  // 1.0 bf16

  const u16t* Krow = Kb + base;
  const u16t* Vrow = Vtb + (size_t)(b * 16 + h) * 131072;  // [64][2048]
  const int kt0 = sp * 32 + 31;

#define STAGE_K(kt_, b_)                                                          \
  gload16(Krow + (size_t)((kt_) * 32 + kline_s) * 1024 + ku_s,                    \
          (char*)Kl + (b_) * 4096 + w * 1024);
#define STAGE_V(kt_, b_)                                                          \
  gload16(Vrow + (size_t)vd_s * 2048 + (kt_) * 32 + vcol_s,                       \
          (char*)Vl + (b_) * 4096 + w * 1024);

  // prologue: K(t0)->k0, V(t0)->v0, K(t0-1 or t0)->k1   [oldest..newest]
  const int ktp = (n > 1) ? kt0 - 1 : kt0;
  STAGE_K(kt0, 0)
  STAGE_V(kt0, 0)
  STAGE_K(ktp, 1)

  for (int it = 0; it < n; ++it) {
    const int kt = kt0 - it;
    const int kbuf = it % 3, vbuf = it & 1;
    // own-tile K,V are the 2 oldest; next K may stay in flight
    if (it == n - 1) { asm volatile("s_waitcnt vmcnt(0)" ::: "memory"); }
    else             { asm volatile("s_waitcnt vmcnt(1)" ::: "memory"); }
    __builtin_amdgcn_s_barrier();   // all waves: tile staged, prev compute done
    asm volatile("" ::: "memory");  // fence IR motion across the barrier
    if (it + 1 < n) STAGE_V(kt - 1, vbuf ^ 1)   // V first (keeps wait at vmcnt(1))
    if (it + 2 < n) STAGE_K(kt - 2, (it + 2) % 3)
    if (it) mj += d32;              // local-bias coordinate shift

    const char* KB = (const char*)Kl + kbuf * 4096;
    const char* VB = (const char*)Vl + vbuf * 4096;

    f32x4 st[2];
#pragma unroll
    for (int t = 0; t < 2; ++t) {
      st[t] = __builtin_amdgcn_mfma_f32_16x16x32_bf16(
          *(const bf16x8*)(KB + koff[t][0]), qf0, cv[t], 0, 0, 0);
      st[t] = __builtin_amdgcn_mfma_f32_16x16x32_bf16(
          *(const bf16x8*)(KB + koff[t][1]), qf1, st[t], 0, 0, 0);
    }

    const float m1 = max3f(st[0][0], st[0][1], st[0][2]);
    const float m2 = max3f(st[0][3], st[1][0], st[1][1]);
    const float m3 = max3f(st[1][2], st[1][3], m1);
    const float tm = fmaxf(m2, m3);
    if (__any(tm > mj)) {  // rare: reverse order => max found in first tiles
      float tr = fmaxf(tm, __shfl_xor(tm, 16));
      tr = fmaxf(tr, __shfl_xor(tr, 32));
      const float mn = fmaxf(mj, tr);
      const float corr = exp2_fast(mj - mn);
#pragma unroll
      for (int d = 0; d < 4; ++d) {
        oc[d][0] *= corr; oc[d][1] *= corr; oc[d][2] *= corr; oc[d][3] *= corr;
      }
      sacc[0] *= corr; sacc[1] *= corr; sacc[2] *= corr; sacc[3] *= corr;
      mj = mn;
    }

    float pe[8];
#pragma unroll
    for (int t = 0; t < 2; ++t)
#pragma unroll
      for (int i = 0; i < 4; ++i) pe[t * 4 + i] = exp2_fast(st[t][i] - mj);
    union { bf16x8 v; unsigned q[4]; } pb;
#pragma unroll
    for (int j = 0; j < 4; ++j) pb.q[j] = cvt_pk_bf16(pe[j * 2], pe[j * 2 + 1]);

#pragma unroll
    for (int db = 0; db < 4; ++db)
      oc[db] = __builtin_amdgcn_mfma_f32_16x16x32_bf16(
          *(const bf16x8*)(VB + voff[db]), pb.v, oc[db], 0, 0, 0);
    sacc = __builtin_amdgcn_mfma_f32_16x16x32_bf16(ones.v, pb.v, sacc, 0, 0, 0);
  }
#undef STAGE_K
#undef STAGE_V

  // write unnormalized partial O + (m_global, l); frame shift: last tile processed
  // is kt0-(n-1), so global m = mj + slope2*32*(kt0-n+1).
  u16t* op = (sp ? O1 : O0) + base + (size_t)qpos * 1024;
#pragma unroll
  for (int d = 0; d < 4; ++d) {
    union { bf16x4 v; u16t u[4]; } o4;
#pragma unroll
    for (int i = 0; i < 4; ++i) o4.u[i] = f2bf(oc[d][i]);
    *(bf16x4*)(op + d * 16 + g * 4) = o4.v;
  }
  if (l < 16) {  // g==0 lanes hold per-row m (mj) and l (sacc[0])
    const float m_global = mj + d32 * (float)(kt0 - n + 1);
    ML[((size_t)(sp * 2 + b) * 16 + h) * 2048 + qpos] = float2{m_global, sacc[0]};
  }
}

// ---------------- combine two KV-split partials -> normalized ctx ----------------
__global__ __launch_bounds__(256)
void combine_kernel(u16t* __restrict__ O0 /* in-out: becomes ctx */,
                    const u16t* __restrict__ O1, const float2* __restrict__ ML) {
  const int idx = blockIdx.x * 256 + threadIdx.x;  // 524288 threads x 8 elems
  const int colg = idx & 127, tok = idx >> 7;
  const int b = tok >> 11, s = tok & 2047, h = colg >> 3;
  const float2 ml0 = ML[((size_t)(0 + b) * 16 + h) * 2048 + s];
  const float2 ml1 = ML[((size_t)(2 + b) * 16 + h) * 2048 + s];
  const float M = fmaxf(ml0.x, ml1.x);
  const float e0 = exp2_fast(ml0.x - M), e1 = exp2_fast(ml1.x - M);
  const float invL = 1.f / (ml0.y * e0 + ml1.y * e1);
  const float w0 = e0 * invL, w1 = e1 * invL;
  union { bf16x8 v; u16t u[8]; } a, c, o;
  a.v = *(const bf16x8*)(O0 + (size_t)idx * 8);
  c.v = *(const bf16x8*)(O1 + (size_t)idx * 8);
#pragma unroll
  for (int i = 0; i < 8; ++i) o.u[i] = f2bf(bf2f(a.u[i]) * w0 + bf2f(c.u[i]) * w1);
  *(bf16x8*)(O0 + (size_t)idx * 8) = o.v;
}

extern "C" void kernel_launch(void* const* d_in, const int* in_sizes, int n_in,
                              void* d_out, int out_size, void* d_ws, size_t ws_size,
                              hipStream_t stream) {
  const float* x = (const float*)d_in[0];
  const float* Wq = (const float*)d_in[1];
  const float* bq = (const float*)d_in[2];
  const float* Wk = (const float*)d_in[3];
  const float* bk = (const float*)d_in[4];
  const float* Wv = (const float*)d_in[5];
  const float* bv = (const float*)d_in[6];
  const float* Wo = (const float*)d_in[7];
  const float* bo = (const float*)d_in[8];
  const float* slopes = (const float*)d_in[9];
  if (ws_size < (size_t)(48u << 20)) return;
  char* ws = (char*)d_ws;
  u16t* x_bf = (u16t*)(ws);                  //  8 MB: x bf16 (dead after gemm0)
  u16t* wqkv = (u16t*)(ws + (8u << 20));     //  6 MB: Wq|Wk|Wv (dead after gemm0)
  u16t* wo_bf = (u16t*)(ws + (14u << 20));   //  2 MB: Wo bf16
  u16t* q_bf = (u16t*)(ws + (16u << 20));    // 24 MB: Q | K | Vt bf16
  u16t* ctx_bf = (u16t*)(ws + (40u << 20));  //  8 MB: ctx / split-0 partial
  u16t* part1 = (u16t*)(ws);                 //  8 MB: split-1 partial (reuses x_bf)
  float2* ml = (float2*)(ws + (8u << 20));   //  1 MB: (m,l) per split/row (reuses wqkv)

  cvt5_kernel<<<4096, 256, 0, stream>>>(x, Wq, Wk, Wv, Wo, x_bf, wqkv, wo_bf);
  gemm_kernel<0><<<dim3(32, 24), 256, 0, stream>>>(x_bf, wqkv, bq, bk, bv, (void*)q_bf);
  attn_kernel<<<dim3(32, 32, 2), 256, 0, stream>>>(q_bf, q_bf + 4194304, q_bf + 8388608,
                                                   slopes, ctx_bf, part1, ml);
  combine_kernel<<<2048, 256, 0, stream>>>(ctx_bf, part1, ml);
  gemm_kernel<1><<<dim3(32, 8), 256, 0, stream>>>(ctx_bf, wo_bf, bo, bo, bo, d_out);
}

// Round 8
// 111.113 us; speedup vs baseline: 1.1688x; 1.0444x over previous
//
#include <hip/hip_runtime.h>
#include <stdint.h>

typedef __attribute__((ext_vector_type(8))) short bf16x8;
typedef __attribute__((ext_vector_type(4))) short bf16x4;
typedef __attribute__((ext_vector_type(4))) float f32x4;
typedef unsigned short u16t;

#define DEVINL static __device__ __forceinline__

DEVINL u16t f2bf(float f) {
  union { float f; unsigned u; } v; v.f = f;
  return (u16t)((v.u + 0x7FFFu + ((v.u >> 16) & 1u)) >> 16);  // RNE, inputs finite
}
DEVINL float bf2f(u16t u) {
  union { unsigned u; float f; } v; v.u = ((unsigned)u) << 16; return v.f;
}

DEVINL float exp2_fast(float x) {
  float r; asm("v_exp_f32 %0, %1" : "=v"(r) : "v"(x)); return r;
}
DEVINL unsigned cvt_pk_bf16(float a, float b) {  // lo16=bf16(a), hi16=bf16(b)
  unsigned r; asm("v_cvt_pk_bf16_f32 %0, %1, %2" : "=v"(r) : "v"(a), "v"(b)); return r;
}
DEVINL float max3f(float a, float b, float c) {
  float r; asm("v_max3_f32 %0, %1, %2, %3" : "=v"(r) : "v"(a), "v"(b), "v"(c)); return r;
}

DEVINL void gload16(const void* g, void* l) {
  __builtin_amdgcn_global_load_lds((const __attribute__((address_space(1))) void*)g,
                                   (__attribute__((address_space(3))) void*)l, 16, 0, 0);
}

// ---------------- fp32 -> bf16 convert (all 5 tensors, one launch) ----------------
__global__ __launch_bounds__(256)
void cvt5_kernel(const float* __restrict__ x, const float* __restrict__ wq,
                 const float* __restrict__ wk, const float* __restrict__ wv,
                 const float* __restrict__ wo, u16t* __restrict__ x_bf,
                 u16t* __restrict__ wqkv, u16t* __restrict__ wo_bf) {
  const int bid = blockIdx.x;
  const float* src; u16t* dst; int off;
  if (bid < 2048) { src = x; dst = x_bf; off = bid * 2048; }
  else {
    const int j = bid - 2048, sel = j >> 9;
    off = (j & 511) * 2048;
    if (sel == 0)      { src = wq; dst = wqkv; }
    else if (sel == 1) { src = wk; dst = wqkv + 1048576; }
    else if (sel == 2) { src = wv; dst = wqkv + 2097152; }
    else               { src = wo; dst = wo_bf; }
  }
  const int i = off + threadIdx.x * 8;
  float4 a = *(const float4*)(src + i);
  float4 b = *(const float4*)(src + i + 4);
  union { bf16x8 v; u16t u[8]; } o;
  o.u[0] = f2bf(a.x); o.u[1] = f2bf(a.y); o.u[2] = f2bf(a.z); o.u[3] = f2bf(a.w);
  o.u[4] = f2bf(b.x); o.u[5] = f2bf(b.y); o.u[6] = f2bf(b.z); o.u[7] = f2bf(b.w);
  *(bf16x8*)(dst + i) = o.v;
}

// ---------------- bf16 GEMM: C[M,N] = A[M,K] * Bw[N,K]^T + bias ----------------
// M=4096, K=1024. MODE 0: N=3072 (Wq|Wk|Wv): Q scaled by 0.125*log2(e), V written
// transposed as Vt[b][h][d][s]. MODE 1: N=1024 (Wo), fp32 out.
// launch_bounds(256,3): cap VGPR ~170 so 3 blocks/CU stay resident (LDS 32KB ok).
template <int MODE>
__global__ __launch_bounds__(256, 3)
void gemm_kernel(const u16t* __restrict__ A, const u16t* __restrict__ Bw,
                 const float* __restrict__ bias0, const float* __restrict__ bias1,
                 const float* __restrict__ bias2, void* __restrict__ outp) {
  __shared__ __attribute__((aligned(16))) u16t As[128 * 64];
  __shared__ __attribute__((aligned(16))) u16t Bs[128 * 64];
  const int tid = threadIdx.x;
  const int w = tid >> 6, l = tid & 63;
  const int wm = w >> 1, wn = w & 1;
  const int bm = blockIdx.x, bn = blockIdx.y;
  const int g = l >> 4, r16 = l & 15;
  const int srow = l >> 3, sslot = l & 7;

  f32x4 acc[4][4];
#pragma unroll
  for (int m = 0; m < 4; ++m)
#pragma unroll
    for (int n = 0; n < 4; ++n) acc[m][n] = f32x4{0.f, 0.f, 0.f, 0.f};

  const size_t arow0 = (size_t)bm * 128;
  const size_t brow0 = (size_t)bn * 128;

  for (int kt = 0; kt < 16; ++kt) {
    __syncthreads();
#pragma unroll
    for (int i = 0; i < 4; ++i) {
      const int row = (i * 4 + w) * 8 + srow;
      const int colA = kt * 64 + ((sslot ^ (row & 7)) * 8);
      gload16(A + (arow0 + row) * 1024 + colA, (char*)As + (i * 4 + w) * 1024);
      gload16(Bw + (brow0 + row) * 1024 + colA, (char*)Bs + (i * 4 + w) * 1024);
    }
    asm volatile("s_waitcnt vmcnt(0)" ::: "memory");
    __syncthreads();
#pragma unroll
    for (int kk = 0; kk < 2; ++kk) {
      bf16x8 af[4], bfr[4];
#pragma unroll
      for (int m = 0; m < 4; ++m) {
        const int rr = wm * 64 + m * 16 + r16;
        af[m] = *(const bf16x8*)((const char*)As + rr * 128 + (((kk * 4 + g) ^ (rr & 7)) * 16));
      }
#pragma unroll
      for (int n = 0; n < 4; ++n) {
        const int rr = wn * 64 + n * 16 + r16;
        bfr[n] = *(const bf16x8*)((const char*)Bs + rr * 128 + (((kk * 4 + g) ^ (rr & 7)) * 16));
      }
#pragma unroll
      for (int m = 0; m < 4; ++m)
#pragma unroll
        for (int n = 0; n < 4; ++n)
          acc[m][n] = __builtin_amdgcn_mfma_f32_16x16x32_bf16(af[m], bfr[n], acc[m][n], 0, 0, 0);
    }
  }

  if (MODE == 0) {
    const int mat = bn >> 3;  // 0=Q,1=K,2=V
    if (mat == 2) {
      u16t* vt = (u16t*)outp + 8388608u;
#pragma unroll
      for (int n = 0; n < 4; ++n) {
        const int col = ((bn & 7) * 128) + wn * 64 + n * 16 + r16;  // h*64+d
        const int hh = col >> 6, dd = col & 63;
        const float bv = bias2[col];
#pragma unroll
        for (int m = 0; m < 4; ++m) {
          const int row0 = bm * 128 + wm * 64 + m * 16 + g * 4;
          const int b_ = row0 >> 11, s_ = row0 & 2047;
          union { bf16x4 v; u16t u[4]; } o4;
#pragma unroll
          for (int i = 0; i < 4; ++i) o4.u[i] = f2bf(acc[m][n][i] + bv);
          *(bf16x4*)(vt + ((size_t)(b_ * 16 + hh) * 64 + dd) * 2048 + s_) = o4.v;
        }
      }
    } else {
      const float* bias = (mat == 0) ? bias0 : bias1;
      // Q: fold 1/sqrt(64) * log2(e) so attention works in exp2 domain
      const float scale = (mat == 0) ? 0.18033688f : 1.0f;
      u16t* o = (u16t*)outp + (size_t)mat * 4194304u;
#pragma unroll
      for (int n = 0; n < 4; ++n) {
        const int col = ((bn & 7) * 128) + wn * 64 + n * 16 + r16;
        const float bv = bias[col];
#pragma unroll
        for (int m = 0; m < 4; ++m) {
          const int row = bm * 128 + wm * 64 + m * 16 + g * 4;
#pragma unroll
          for (int i = 0; i < 4; ++i)
            o[(size_t)(row + i) * 1024 + col] = f2bf((acc[m][n][i] + bv) * scale);
        }
      }
    }
  } else {
    float* o = (float*)outp;
#pragma unroll
    for (int n = 0; n < 4; ++n) {
      const int col = bn * 128 + wn * 64 + n * 16 + r16;
      const float bv = bias0[col];
#pragma unroll
      for (int m = 0; m < 4; ++m) {
        const int row = bm * 128 + wm * 64 + m * 16 + g * 4;
#pragma unroll
        for (int i = 0; i < 4; ++i)
          o[(size_t)(row + i) * 1024 + col] = acc[m][n][i] + bv;
      }
    }
  }
}

// ---------------- flash attention with ALiBi, KV-split=2 + windowing + LPT ----------------
// As R7 (exp2 domain, reverse order, bias in MFMA C-init, window = last 26/slope2
// keys, K ring3 + V ring2 LDS 20480B, counted vmcnt(1), ones-MFMA row-sum,
// unnormalized partial O + (m,l)) PLUS:
//  - LPT dispatch: blockIdx.y -> (b, slot); slot decoded to (h, sp) ordered by
//    known block length desc (slopes are analytic 2^(-0.5-h); mapping is perf-only,
//    n still computed from runtime slopes) so long blocks launch first and
//    short/empty ones backfill.
//  - s_setprio(1) around MFMA clusters (T5; attn has wave phase-diversity).
__global__ __launch_bounds__(256, 2)
void attn_kernel(const u16t* __restrict__ Qb, const u16t* __restrict__ Kb,
                 const u16t* __restrict__ Vtb, const float* __restrict__ slopes,
                 u16t* __restrict__ O0, u16t* __restrict__ O1,
                 float2* __restrict__ ML) {
  __shared__ __attribute__((aligned(16))) u16t Kl[3][2048];  // 3 x [32 keys][64 d]
  __shared__ __attribute__((aligned(16))) u16t Vl[2][2048];  // 2 x 32 lines x 128B
  const int tid = threadIdx.x;
  const int w = tid >> 6, l = tid & 63;
  const int g = l >> 4, r = l & 15;
  const int qt = blockIdx.x;
  // ---- LPT slot decode: lengths 32x19, 26, 19, 13, 7, 4, 2, 1, 0x6 ----
  const int slot = blockIdx.y >> 1, b = blockIdx.y & 1;
  int h, sp;
  if (slot < 10)       { h = 6 + slot;  sp = 1; }   // len 32 (sp1 h6..15)
  else if (slot < 19)  { h = slot - 3;  sp = 0; }   // len 32 (sp0 h7..15)
  else if (slot == 19) { h = 5; sp = 1; }           // 26
  else if (slot == 20) { h = 6; sp = 0; }           // 19
  else if (slot < 26)  { h = 25 - slot; sp = 1; }   // 13,7,4,2,1 (h4..0)
  else                 { h = slot - 26; sp = 0; }   // len 0
  const float slope2 = slopes[h] * 1.44269504f;
  const int qpos = qt * 64 + w * 16 + r;
  const size_t base = (size_t)b * 2097152 + (size_t)h * 64;

  // ---- ALiBi window: only the last W=26/slope2 keys matter ----
  const float Wkeys = 26.0f / slope2;
  const int wt = (int)ceilf(Wkeys * 0.03125f);          // tiles from the end
  const int n = sp ? (wt < 32 ? wt : 32)
                   : (wt - 32 < 0 ? 0 : (wt - 32 < 32 ? wt - 32 : 32));
  if (n == 0) {  // this split contributes nothing measurable
    if (l < 16)
      ML[((size_t)(sp * 2 + b) * 16 + h) * 2048 + qpos] = float2{-3.0e38f, 0.f};
    return;
  }

  const u16t* qrow = Qb + base + (size_t)qpos * 1024;
  const bf16x8 qf0 = *(const bf16x8*)(qrow + g * 8);
  const bf16x8 qf1 = *(const bf16x8*)(qrow + 32 + g * 8);
  asm volatile("s_waitcnt vmcnt(0)" ::: "memory");  // Q in regs; vmcnt clean

  // K A-frag offsets: row perm sigma(r)=8*(r>>2)+(r&3), tiles toff {0,4};
  // mask (row&3)^((row>>1)&4) — proven 0-conflict (R3 geometry).
  const int sig = 8 * (r >> 2) + (r & 3);
  const int toffs[2] = {0, 4};
  int koff[2][2], voff[4];
#pragma unroll
  for (int t = 0; t < 2; ++t) {
    const int row = toffs[t] + sig;
    const int mk = (row & 3) ^ ((row >> 1) & 4);
#pragma unroll
    for (int hh = 0; hh < 2; ++hh) koff[t][hh] = row * 128 + (((hh * 4 + g) ^ mk) * 16);
  }
  // V read: lane (g,r), db: d=16db+r; line=8db+(r>>1); slot=((r&1)<<2|g)^((r>>1)&3)
#pragma unroll
  for (int db = 0; db < 4; ++db)
    voff[db] = (8 * db + (r >> 1)) * 128 + ((((((r & 1) << 2) | g)) ^ ((r >> 1) & 3)) * 16);

  // staging source geometry (LDS dest linear, source pre-swizzled)
  const int kline_s = w * 8 + (l >> 3);             // 0..31
  const int ku_s = ((l & 7) ^ ((kline_s & 3) ^ ((kline_s >> 1) & 4))) * 8;
  const int vu_s = (l & 7) ^ (kline_s & 3);         // V: u = slot ^ (line&3)
  const int vd_s = 2 * kline_s + (vu_s >> 2);       // global d row
  const int vcol_s = (vu_s & 3) * 8;                // key sub-offset

  // ALiBi C-init: cv[t][i] = slope2 * local_j for st[t][i] <-> key toff[t]+8g+i
  f32x4 cv[2];
#pragma unroll
  for (int t = 0; t < 2; ++t)
#pragma unroll
    for (int i = 0; i < 4; ++i) cv[t][i] = slope2 * (float)(toffs[t] + 8 * g + i);

  const float d32 = slope2 * 32.f;
  float mj = -3.0e38f;
  f32x4 oc[4], sacc;
#pragma unroll
  for (int d = 0; d < 4; ++d) oc[d] = f32x4{0.f, 0.f, 0.f, 0.f};
  sacc = f32x4{0.f, 0.f, 0.f, 0.f};
  union { bf16x8 v; u16t u[8]; } ones;
#pragma unroll
  for (int i = 0; i < 8; ++i) ones.u[i] = 0x3F80;  // 1.0 bf16

  const u16t* Krow = Kb + base;
  const u16t* Vrow = Vtb + (size_t)(b * 16 + h) * 131072;  // [64][2048]
  const int kt0 = sp * 32 + 31;

#define STAGE_K(kt_, b_)                                                          \
  gload16(Krow + (size_t)((kt_) * 32 + kline_s) * 1024 + ku_s,                    \
          (char*)Kl + (b_) * 4096 + w * 1024);
#define STAGE_V(kt_, b_)                                                          \
  gload16(Vrow + (size_t)vd_s * 2048 + (kt_) * 32 + vcol_s,                       \
          (char*)Vl + (b_) * 4096 + w * 1024);

  // prologue: K(t0)->k0, V(t0)->v0, K(t0-1 or t0)->k1   [oldest..newest]
  const int ktp = (n > 1) ? kt0 - 1 : kt0;
  STAGE_K(kt0, 0)
  STAGE_V(kt0, 0)
  STAGE_K(ktp, 1)

  for (int it = 0; it < n; ++it) {
    const int kt = kt0 - it;
    const int kbuf = it % 3, vbuf = it & 1;
    // own-tile K,V are the 2 oldest; next K may stay in flight
    if (it == n - 1) { asm volatile("s_waitcnt vmcnt(0)" ::: "memory"); }
    else             { asm volatile("s_waitcnt vmcnt(1)" ::: "memory"); }
    __builtin_amdgcn_s_barrier();   // all waves: tile staged, prev compute done
    asm volatile("" ::: "memory");  // fence IR motion across the barrier
    if (it + 1 < n) STAGE_V(kt - 1, vbuf ^ 1)   // V first (keeps wait at vmcnt(1))
    if (it + 2 < n) STAGE_K(kt - 2, (it + 2) % 3)
    if (it) mj += d32;              // local-bias coordinate shift

    const char* KB = (const char*)Kl + kbuf * 4096;
    const char* VB = (const char*)Vl + vbuf * 4096;

    f32x4 st[2];
    __builtin_amdgcn_s_setprio(1);
#pragma unroll
    for (int t = 0; t < 2; ++t) {
      st[t] = __builtin_amdgcn_mfma_f32_16x16x32_bf16(
          *(const bf16x8*)(KB + koff[t][0]), qf0, cv[t], 0, 0, 0);
      st[t] = __builtin_amdgcn_mfma_f32_16x16x32_bf16(
          *(const bf16x8*)(KB + koff[t][1]), qf1, st[t], 0, 0, 0);
    }
    __builtin_amdgcn_s_setprio(0);

    const float m1 = max3f(st[0][0], st[0][1], st[0][2]);
    const float m2 = max3f(st[0][3], st[1][0], st[1][1]);
    const float m3 = max3f(st[1][2], st[1][3], m1);
    const float tm = fmaxf(m2, m3);
    if (__any(tm > mj)) {  // rare: reverse order => max found in first tiles
      float tr = fmaxf(tm, __shfl_xor(tm, 16));
      tr = fmaxf(tr, __shfl_xor(tr, 32));
      const float mn = fmaxf(mj, tr);
      const float corr = exp2_fast(mj - mn);
#pragma unroll
      for (int d = 0; d < 4; ++d) {
        oc[d][0] *= corr; oc[d][1] *= corr; oc[d][2] *= corr; oc[d][3] *= corr;
      }
      sacc[0] *= corr; sacc[1] *= corr; sacc[2] *= corr; sacc[3] *= corr;
      mj = mn;
    }

    float pe[8];
#pragma unroll
    for (int t = 0; t < 2; ++t)
#pragma unroll
      for (int i = 0; i < 4; ++i) pe[t * 4 + i] = exp2_fast(st[t][i] - mj);
    union { bf16x8 v; unsigned q[4]; } pb;
#pragma unroll
    for (int j = 0; j < 4; ++j) pb.q[j] = cvt_pk_bf16(pe[j * 2], pe[j * 2 + 1]);

    __builtin_amdgcn_s_setprio(1);
#pragma unroll
    for (int db = 0; db < 4; ++db)
      oc[db] = __builtin_amdgcn_mfma_f32_16x16x32_bf16(
          *(const bf16x8*)(VB + voff[db]), pb.v, oc[db], 0, 0, 0);
    sacc = __builtin_amdgcn_mfma_f32_16x16x32_bf16(ones.v, pb.v, sacc, 0, 0, 0);
    __builtin_amdgcn_s_setprio(0);
  }
#undef STAGE_K
#undef STAGE_V

  // write unnormalized partial O + (m_global, l); frame shift: last tile processed
  // is kt0-(n-1), so global m = mj + slope2*32*(kt0-n+1).
  u16t* op = (sp ? O1 : O0) + base + (size_t)qpos * 1024;
#pragma unroll
  for (int d = 0; d < 4; ++d) {
    union { bf16x4 v; u16t u[4]; } o4;
#pragma unroll
    for (int i = 0; i < 4; ++i) o4.u[i] = f2bf(oc[d][i]);
    *(bf16x4*)(op + d * 16 + g * 4) = o4.v;
  }
  if (l < 16) {  // g==0 lanes hold per-row m (mj) and l (sacc[0])
    const float m_global = mj + d32 * (float)(kt0 - n + 1);
    ML[((size_t)(sp * 2 + b) * 16 + h) * 2048 + qpos] = float2{m_global, sacc[0]};
  }
}

// ---------------- combine two KV-split partials -> normalized ctx ----------------
__global__ __launch_bounds__(256)
void combine_kernel(u16t* __restrict__ O0 /* in-out: becomes ctx */,
                    const u16t* __restrict__ O1, const float2* __restrict__ ML) {
  const int idx = blockIdx.x * 256 + threadIdx.x;  // 524288 threads x 8 elems
  const int colg = idx & 127, tok = idx >> 7;
  const int b = tok >> 11, s = tok & 2047, h = colg >> 3;
  const float2 ml0 = ML[((size_t)(0 + b) * 16 + h) * 2048 + s];
  const float2 ml1 = ML[((size_t)(2 + b) * 16 + h) * 2048 + s];
  const float M = fmaxf(ml0.x, ml1.x);
  const float e0 = exp2_fast(ml0.x - M), e1 = exp2_fast(ml1.x - M);
  const float invL = 1.f / (ml0.y * e0 + ml1.y * e1);
  const float w0 = e0 * invL, w1 = e1 * invL;
  union { bf16x8 v; u16t u[8]; } a, c, o;
  a.v = *(const bf16x8*)(O0 + (size_t)idx * 8);
  c.v = *(const bf16x8*)(O1 + (size_t)idx * 8);
#pragma unroll
  for (int i = 0; i < 8; ++i) o.u[i] = f2bf(bf2f(a.u[i]) * w0 + bf2f(c.u[i]) * w1);
  *(bf16x8*)(O0 + (size_t)idx * 8) = o.v;
}

extern "C" void kernel_launch(void* const* d_in, const int* in_sizes, int n_in,
                              void* d_out, int out_size, void* d_ws, size_t ws_size,
                              hipStream_t stream) {
  const float* x = (const float*)d_in[0];
  const float* Wq = (const float*)d_in[1];
  const float* bq = (const float*)d_in[2];
  const float* Wk = (const float*)d_in[3];
  const float* bk = (const float*)d_in[4];
  const float* Wv = (const float*)d_in[5];
  const float* bv = (const float*)d_in[6];
  const float* Wo = (const float*)d_in[7];
  const float* bo = (const float*)d_in[8];
  const float* slopes = (const float*)d_in[9];
  if (ws_size < (size_t)(48u << 20)) return;
  char* ws = (char*)d_ws;
  u16t* x_bf = (u16t*)(ws);                  //  8 MB: x bf16 (dead after gemm0)
  u16t* wqkv = (u16t*)(ws + (8u << 20));     //  6 MB: Wq|Wk|Wv (dead after gemm0)
  u16t* wo_bf = (u16t*)(ws + (14u << 20));   //  2 MB: Wo bf16
  u16t* q_bf = (u16t*)(ws + (16u << 20));    // 24 MB: Q | K | Vt bf16
  u16t* ctx_bf = (u16t*)(ws + (40u << 20));  //  8 MB: ctx / split-0 partial
  u16t* part1 = (u16t*)(ws);                 //  8 MB: split-1 partial (reuses x_bf)
  float2* ml = (float2*)(ws + (8u << 20));   //  1 MB: (m,l) per split/row (reuses wqkv)

  cvt5_kernel<<<4096, 256, 0, stream>>>(x, Wq, Wk, Wv, Wo, x_bf, wqkv, wo_bf);
  gemm_kernel<0><<<dim3(32, 24), 256, 0, stream>>>(x_bf, wqkv, bq, bk, bv, (void*)q_bf);
  attn_kernel<<<dim3(32, 64), 256, 0, stream>>>(q_bf, q_bf + 4194304, q_bf + 8388608,
                                                slopes, ctx_bf, part1, ml);
  combine_kernel<<<2048, 256, 0, stream>>>(ctx_bf, part1, ml);
  gemm_kernel<1><<<dim3(32, 8), 256, 0, stream>>>(ctx_bf, wo_bf, bo, bo, bo, d_out);
}